// Round 4
// baseline (447.912 us; speedup 1.0000x reference)
//
#include <hip/hip_runtime.h>
#include <math.h>

// B=2, H=16, S=2048, DK=64
#define S_LEN 2048
#define NCH   32          // S/64 chunks
#define N_BH  32

typedef short bf16x8 __attribute__((ext_vector_type(8)));
typedef float f32x4  __attribute__((ext_vector_type(4)));
typedef unsigned short u16;
typedef unsigned long long u64;

#define MFMA32(a,b,c) __builtin_amdgcn_mfma_f32_16x16x32_bf16((a),(b),(c),0,0,0)

// (1/sqrt(64)) * log2(e): scores in log2 units; exp2f = one v_exp_f32.
#define SC        0.18033688011112042f
// masked score in log2 units: exp2(-30)=9.3e-10 (negligible vs unmasked;
// a fully-masked column degrades to EXACT uniform 1/2048).
#define MASKED_L2 (-30.0f)

__device__ __forceinline__ u16 f2bf_rne(float x) {
  unsigned u = __float_as_uint(x);
  return (u16)((u + 0x7FFF + ((u >> 16) & 1)) >> 16);
}
// hi = bit-truncation, lo = RNE of residual; combined repr error ~2^-17
__device__ __forceinline__ void bfsplit(float x, u16& h, u16& l) {
  unsigned u = __float_as_uint(x);
  h = (u16)(u >> 16);
  float hf = __uint_as_float(u & 0xFFFF0000u);
  l = f2bf_rne(x - hf);
}

// ---------------------------------------------------------------------------
// Pass 0: bit-pack the mask. word (row, wc) = ballot over k = wc*64 + lane.
// ---------------------------------------------------------------------------
__global__ __launch_bounds__(256) void pack_mask(
    const int* __restrict__ mask, u64* __restrict__ bits) {
  const int word = blockIdx.x * 4 + (threadIdx.x >> 6);
  const int lane = threadIdx.x & 63;
  const int row = word >> 5, wc = word & 31;
  int m = mask[(size_t)row * S_LEN + wc * 64 + lane];
  u64 b = __ballot(m != 0);
  if (lane == 0) bits[word] = b;
}

// ---------------------------------------------------------------------------
// Pass A: il[k] = 1 / sum_q exp2(s~[q,k])  (masked -> 2^-30), no max needed.
// Swapped MFMA (A=K, B=Q): lane (c,g) reg r -> s~(k=16w+4g+r, q=qs*16+c).
// Block=(kc,bh); wave w owns 16 k's (K-frags in regs); streams all q.
// ZERO LDS, ZERO barriers.
// ---------------------------------------------------------------------------
__global__ __launch_bounds__(256) void passA_colsum(
    const float* __restrict__ Q, const float* __restrict__ K,
    const u64* __restrict__ mbits, float* __restrict__ il_out) {
  const int tid = threadIdx.x;
  const int lane = tid & 63;
  const int w = tid >> 6;
  const int c = lane & 15;
  const int g = lane >> 4;
  const int kc = blockIdx.x;
  const int bh = blockIdx.y;

  const float* Qb = Q + (size_t)bh * S_LEN * 64;
  const float* Kb = K + (size_t)bh * S_LEN * 64;

  // A-frags: K rows kc*64 + w*16 + c, hi/lo split, both d-halves.
  bf16x8 kah[2], kal[2];
  {
    const int krow = kc * 64 + w * 16 + c;
#pragma unroll
    for (int h = 0; h < 2; ++h) {
      const float* src = Kb + (size_t)krow * 64 + h * 32 + g * 8;
      float4 x = *(const float4*)(src);
      float4 y = *(const float4*)(src + 4);
      float xs[8] = {x.x, x.y, x.z, x.w, y.x, y.y, y.z, y.w};
#pragma unroll
      for (int e = 0; e < 8; ++e) {
        u16 hh, ll; bfsplit(xs[e], hh, ll);
        kah[h][e] = (short)hh; kal[h][e] = (short)ll;
      }
    }
  }

  float lp[4] = {0.f, 0.f, 0.f, 0.f};
  const int shift = w * 16 + g * 4;

  for (int qs = 0; qs < S_LEN / 16; ++qs) {
    const int qrow = qs * 16 + c;
    bf16x8 qbh[2], qbl[2];
#pragma unroll
    for (int h = 0; h < 2; ++h) {
      const float* src = Qb + (size_t)qrow * 64 + h * 32 + g * 8;
      float4 x = *(const float4*)(src);
      float4 y = *(const float4*)(src + 4);
      float xs[8] = {x.x, x.y, x.z, x.w, y.x, y.y, y.z, y.w};
#pragma unroll
      for (int e = 0; e < 8; ++e) {
        u16 hh, ll; bfsplit(xs[e] * SC, hh, ll);
        qbh[h][e] = (short)hh; qbl[h][e] = (short)ll;
      }
    }
    f32x4 acc = {0.f, 0.f, 0.f, 0.f};
#pragma unroll
    for (int h = 0; h < 2; ++h) {        // IDENTICAL order in pass C
      acc = MFMA32(kah[h], qbh[h], acc);
      acc = MFMA32(kal[h], qbh[h], acc);
      acc = MFMA32(kah[h], qbl[h], acc);
    }
    u64 mw = mbits[(size_t)qrow * NCH + kc];
    unsigned nib = (unsigned)(mw >> shift) & 0xFu;
#pragma unroll
    for (int r = 0; r < 4; ++r) {
      float s = ((nib >> r) & 1) ? MASKED_L2 : acc[r];
      lp[r] += exp2f(s);
    }
  }
  // sum over the 16 c-lanes of each g-group
#pragma unroll
  for (int off = 1; off < 16; off <<= 1)
#pragma unroll
    for (int r = 0; r < 4; ++r) lp[r] += __shfl_xor(lp[r], off, 64);
  if (c == 0) {
    float4 o = {1.f / lp[0], 1.f / lp[1], 1.f / lp[2], 1.f / lp[3]};
    *(float4*)(il_out + (size_t)bh * S_LEN + kc * 64 + w * 16 + g * 4) = o;
  }
}

// ---------------------------------------------------------------------------
// Pass C: out[q,d] = sum_k exp2(s~[q,k]) * (il[k]*v[k,d]).
// Swapped QK: lane (c,g) reg r holds s~(k=16kt+4g+r, q=c). P goes through a
// per-wave swizzled LDS tile (one ushort4 store per kt) and comes back as
// the 16x16x32 B-frag (b128, bank-balanced). PV = 8 x MFMA32 per chunk.
// il folded into V (W = il*V) during staging. Wave w owns q rows 16w..16w+15.
// ---------------------------------------------------------------------------
__global__ __launch_bounds__(256) void passC_out(
    const float* __restrict__ Q, const float* __restrict__ K,
    const float* __restrict__ V, const u64* __restrict__ mbits,
    const float* __restrict__ il_in, float* __restrict__ out) {
  __shared__ u16 kh_s[4096];
  __shared__ u16 kl_s[4096];
  __shared__ u16 vt_s[4096];   // vt_s[d][k] = bf16(il[k]*V[k][d]), swizzled
  __shared__ u16 p_s[4096];    // per-wave [16 q][64 k] bf16, swizzled

  const int tid = threadIdx.x;
  const int lane = tid & 63;
  const int w = tid >> 6;
  const int c = lane & 15;
  const int g = lane >> 4;
  const int qc = blockIdx.x;
  const int bh = blockIdx.y;

  const float* Qb = Q + (size_t)bh * S_LEN * 64;
  const float* Kb = K + (size_t)bh * S_LEN * 64;
  const float* Vb = V + (size_t)bh * S_LEN * 64;

  // B-frags: this wave's 16 Q rows (scaled + split), in regs for the block.
  bf16x8 qbh[2], qbl[2];
  {
    const int qrow = qc * 64 + w * 16 + c;
#pragma unroll
    for (int h = 0; h < 2; ++h) {
      const float* src = Qb + (size_t)qrow * 64 + h * 32 + g * 8;
      float4 x = *(const float4*)(src);
      float4 y = *(const float4*)(src + 4);
      float xs[8] = {x.x, x.y, x.z, x.w, y.x, y.y, y.z, y.w};
#pragma unroll
      for (int e = 0; e < 8; ++e) {
        u16 hh, ll; bfsplit(xs[e] * SC, hh, ll);
        qbh[h][e] = (short)hh; qbl[h][e] = (short)ll;
      }
    }
  }

  f32x4 oacc[4];
#pragma unroll
  for (int dt = 0; dt < 4; ++dt) oacc[dt] = (f32x4){0.f, 0.f, 0.f, 0.f};

  const int slot = tid & 15, r0 = tid >> 4;   // K staging roles
  const int kv = tid & 63, dblk = tid >> 6;   // V staging roles
  const int swc = (c & 7) << 3;
  const int pbase = w * 1024 + c * 64;

  for (int kc = 0; kc < NCH; ++kc) {
    __syncthreads();
    // stage K split (hi/lo), XOR-swizzled rows
#pragma unroll
    for (int p = 0; p < 4; ++p) {
      const int row = p * 16 + r0;
      float4 kx = *(const float4*)(Kb + (size_t)(kc * 64 + row) * 64 + slot * 4);
      float xs[4] = {kx.x, kx.y, kx.z, kx.w};
      u16 ha[4], la[4];
#pragma unroll
      for (int e = 0; e < 4; ++e) bfsplit(xs[e], ha[e], la[e]);
      const int idx = row * 64 + ((slot * 4) ^ ((row & 7) << 3));
      *(ushort4*)(kh_s + idx) = make_ushort4(ha[0], ha[1], ha[2], ha[3]);
      *(ushort4*)(kl_s + idx) = make_ushort4(la[0], la[1], la[2], la[3]);
    }
    // stage W = il[k]*V, transposed -> vt_s[d][k] bf16, swizzled
    {
      const float ilk = il_in[(size_t)bh * S_LEN + kc * 64 + kv];
#pragma unroll
      for (int u = 0; u < 4; ++u) {
        float4 vv = *(const float4*)(Vb + (size_t)(kc * 64 + kv) * 64 + dblk * 16 + u * 4);
        float xs[4] = {vv.x, vv.y, vv.z, vv.w};
#pragma unroll
        for (int e = 0; e < 4; ++e) {
          const int d = dblk * 16 + u * 4 + e;
          vt_s[d * 64 + (kv ^ ((d & 7) << 3))] = f2bf_rne(xs[e] * ilk);
        }
      }
    }
    __syncthreads();

    const u64 mw = mbits[(size_t)(qc * 64 + w * 16 + c) * NCH + kc];

    // QK^T + mask + exp2 -> P (per-wave LDS tile)
#pragma unroll
    for (int kt = 0; kt < 4; ++kt) {
      const int kbase = (16 * kt + c) * 64;
      bf16x8 akh[2], akl[2];
#pragma unroll
      for (int h = 0; h < 2; ++h) {
        const int off = (h * 32 + g * 8) ^ swc;
        akh[h] = *(const bf16x8*)(kh_s + kbase + off);
        akl[h] = *(const bf16x8*)(kl_s + kbase + off);
      }
      f32x4 acc = {0.f, 0.f, 0.f, 0.f};
#pragma unroll
      for (int h = 0; h < 2; ++h) {      // IDENTICAL order to pass A
        acc = MFMA32(akh[h], qbh[h], acc);
        acc = MFMA32(akl[h], qbh[h], acc);
        acc = MFMA32(akh[h], qbl[h], acc);
      }
      const unsigned nib = (unsigned)(mw >> (kt * 16 + g * 4)) & 0xFu;
      u16 pb[4];
#pragma unroll
      for (int r = 0; r < 4; ++r) {
        const float s = ((nib >> r) & 1) ? MASKED_L2 : acc[r];
        pb[r] = f2bf_rne(exp2f(s));
      }
      // store P[k=16kt+4g+r][q=c] at row q=c, col k, XOR-swizzled by c
      *(ushort4*)(p_s + pbase + ((kt * 16 + g * 4) ^ swc)) =
          make_ushort4(pb[0], pb[1], pb[2], pb[3]);
    }
    __syncthreads();

    // PV: oacc[dt] += W^T[16dt.., k-slice] * P[k-slice, q]  (2 slices of 32)
#pragma unroll
    for (int s = 0; s < 2; ++s) {
      const int koff = (s * 32 + 8 * g) ^ swc;
      bf16x8 pb8 = *(const bf16x8*)(p_s + pbase + koff);
#pragma unroll
      for (int dt = 0; dt < 4; ++dt) {
        bf16x8 av = *(const bf16x8*)(vt_s + (16 * dt + c) * 64 + koff);
        oacc[dt] = MFMA32(av, pb8, oacc[dt]);
      }
    }
  }

  // epilogue: lane (c,g) owns row q = qc*64+w*16+c, cols d = 16dt+4g+r
  float* ob = out + ((size_t)bh * S_LEN + qc * 64 + w * 16 + c) * 64;
#pragma unroll
  for (int dt = 0; dt < 4; ++dt) {
    float4 o = {oacc[dt][0], oacc[dt][1], oacc[dt][2], oacc[dt][3]};
    *(float4*)(ob + dt * 16 + g * 4) = o;
  }
}

extern "C" void kernel_launch(void* const* d_in, const int* in_sizes, int n_in,
                              void* d_out, int out_size, void* d_ws, size_t ws_size,
                              hipStream_t stream) {
  (void)in_sizes; (void)n_in; (void)out_size; (void)ws_size;
  const float* q = (const float*)d_in[0];
  const float* k = (const float*)d_in[1];
  const float* v = (const float*)d_in[2];
  const int* mask = (const int*)d_in[3];
  float* out = (float*)d_out;

  // ws: mask bits [2048][32] u64 (512KB) + il [32*2048] f32 (256KB)
  u64* mbits = (u64*)d_ws;
  float* il = (float*)(mbits + (size_t)S_LEN * NCH);

  pack_mask<<<dim3(S_LEN * NCH / 4), 256, 0, stream>>>(mask, mbits);
  dim3 grid(NCH, N_BH);
  passA_colsum<<<grid, 256, 0, stream>>>(q, k, mbits, il);
  passC_out<<<grid, 256, 0, stream>>>(q, k, v, mbits, il, out);
}